// Round 3
// baseline (730.413 us; speedup 1.0000x reference)
//
#include <hip/hip_runtime.h>

// ---------------------------------------------------------------------------
// MHAMixer: 2 linear heads + 2 conv1d(k=3) heads -> attention -> concat -> proj
// GEMMs (proj/final): bf16 MFMA 16x16x32, 128x128 tile, BK=32, global_load_lds
// staging (m97 structure), B pre-transposed to [N][K].
// R2: attention middle (QK^T -> softmax -> PV) fused into ONE flash kernel.
// Two-pass per block: pass1 computes running row (max, sum-exp) stats in regs;
// pass2 recomputes S, writes normalized f32 att directly (mandatory output),
// feeds p-bf16 through a swizzled LDS tile into the PV MFMA. The e/S matrix
// never round-trips HBM. All LDS tiles XOR-swizzled (2-way = free).
// ---------------------------------------------------------------------------

using bf16_t = __bf16;
using bf16x8 = __attribute__((ext_vector_type(8))) __bf16;
using f32x4  = __attribute__((ext_vector_type(4))) float;

#define NB   16
#define SL   1024
#define DIN  512
#define DQK  128
#define NH   4

#define BK 32

constexpr size_t XPAD_ROWS  = (size_t)NB * (SL + 2);          // 16*1026
constexpr size_t XPAD_PER   = XPAD_ROWS * DIN;                // 8,404,992
constexpr size_t XPAD_ELEMS = 3 * XPAD_PER;
constexpr size_t WT_ELEMS   = (size_t)3 * NH * 3 * DQK * DIN; // 2,359,296
constexpr size_t PWT_ELEMS  = (size_t)DIN * DIN;              // 262,144
constexpr size_t BIAS_ELEMS = (size_t)3 * NH * DQK;           // 1536
constexpr size_t QH_ELEMS   = (size_t)NH * NB * SL * DQK;     // 8,388,608
constexpr size_t CAT_ELEMS  = (size_t)NB * SL * (NH * DQK);   // 8,388,608

#define INV_SQRT_DK 0.08838834764831845f

__device__ __forceinline__ void load_lds_16B(const void* g, void* l) {
  __builtin_amdgcn_global_load_lds((const __attribute__((address_space(1))) void*)g,
                                   (__attribute__((address_space(3))) void*)l, 16, 0, 0);
}

// 128x128 output tile, 4 waves (2x2), each wave 4x4 of 16x16x32 MFMA.
// A: [M][K] row-major (lda elems), Bt: [N][K] row-major (ldb elems). K % 32 == 0.
__device__ __forceinline__ void gemm_core(const bf16_t* __restrict__ Ab, int lda,
                                          const bf16_t* __restrict__ Bb, int ldb,
                                          int K, f32x4 acc[4][4],
                                          bf16_t* lgA, bf16_t* lgB) {
  const int tid  = threadIdx.x;
  const int wave = tid >> 6;
  const int lane = tid & 63;
  const int quad = lane >> 4;
  const int l16  = lane & 15;
  const int wr   = wave >> 1;
  const int wc   = wave & 1;
  const int lrow = lane >> 2;        // 0..15: row within 16-row chunk
  const int lcol = (lane & 3) << 3;  // 0,8,16,24: element offset within row

  for (int k0 = 0; k0 < K; k0 += BK) {
    __syncthreads();   // previous iter's LDS reads done before overwrite
#pragma unroll
    for (int c = 0; c < 2; ++c) {
      const int chunk = wave * 2 + c;           // 8 chunks of 16 rows
      const int r = chunk * 16 + lrow;
      load_lds_16B(Ab + (size_t)r * lda + k0 + lcol, lgA + chunk * 512);
      load_lds_16B(Bb + (size_t)r * ldb + k0 + lcol, lgB + chunk * 512);
    }
    __syncthreads();   // drains vmcnt (compiler) -> LDS tiles visible
    bf16x8 af[4], bfr[4];
#pragma unroll
    for (int i = 0; i < 4; ++i)
      af[i] = *(const bf16x8*)(lgA + (wr * 64 + i * 16 + l16) * BK + quad * 8);
#pragma unroll
    for (int i = 0; i < 4; ++i)
      bfr[i] = *(const bf16x8*)(lgB + (wc * 64 + i * 16 + l16) * BK + quad * 8);
#pragma unroll
    for (int mi = 0; mi < 4; ++mi)
#pragma unroll
      for (int ni = 0; ni < 4; ++ni)
        acc[mi][ni] = __builtin_amdgcn_mfma_f32_16x16x32_bf16(af[mi], bfr[ni],
                                                              acc[mi][ni], 0, 0, 0);
  }
}

#define GEMM_PROLOGUE()                                    \
  __shared__ __align__(16) bf16_t lgA[128 * BK];           \
  __shared__ __align__(16) bf16_t lgB[128 * BK];           \
  f32x4 acc[4][4];                                         \
  {                                                        \
    f32x4 z = {0.f, 0.f, 0.f, 0.f};                        \
    _Pragma("unroll") for (int i = 0; i < 4; ++i)          \
      _Pragma("unroll") for (int j = 0; j < 4; ++j)        \
        acc[i][j] = z;                                     \
  }

#define EPILOGUE_VARS()                                    \
  const int wave = threadIdx.x >> 6;                       \
  const int lane = threadIdx.x & 63;                       \
  const int quad = lane >> 4;                              \
  const int l16  = lane & 15;                              \
  const int wr   = wave >> 1;                              \
  const int wc   = wave & 1;

// --------------------------- prep kernels ----------------------------------

// pad+cast q/k/v -> bf16 [3][NB][1026][DIN], rows 0 and 1025 zeroed per batch
__global__ void cast_pad_kernel(const float* __restrict__ q,
                                const float* __restrict__ k,
                                const float* __restrict__ v,
                                bf16_t* __restrict__ xpad) {
  size_t i = (size_t)blockIdx.x * blockDim.x + threadIdx.x;  // 8-elem group
  if (i >= XPAD_ELEMS / 8) return;
  int    s    = (int)(i / (XPAD_PER / 8));
  size_t r    = i % (XPAD_PER / 8);
  size_t rowg = r >> 6;                 // b*1026 + padded row
  int    c0   = (int)(r & 63) * 8;
  size_t b    = rowg / (SL + 2);
  int    row  = (int)(rowg % (SL + 2));
  const float* src = (s == 0) ? q : ((s == 1) ? k : v);
  bf16x8 o;
  if (row == 0 || row == SL + 1) {
#pragma unroll
    for (int j = 0; j < 8; ++j) o[j] = (bf16_t)0.f;
  } else {
    const float* p = src + ((b * SL) + row - 1) * DIN + c0;
    const float4 f0 = ((const float4*)p)[0];
    const float4 f1 = ((const float4*)p)[1];
    o[0] = (bf16_t)f0.x; o[1] = (bf16_t)f0.y; o[2] = (bf16_t)f0.z; o[3] = (bf16_t)f0.w;
    o[4] = (bf16_t)f1.x; o[5] = (bf16_t)f1.y; o[6] = (bf16_t)f1.z; o[7] = (bf16_t)f1.w;
  }
  *(bf16x8*)(xpad + i * 8) = o;
}

// Wt  [3][4][3][DQK][DIN] bf16 (B^T per src/head/tap; learnable: tap1 only)
// pwt [DIN][DIN] bf16 = proj_w^T ; bias [3][4][DQK] f32
__global__ void prep_w_kernel(const float* __restrict__ lw_q, const float* __restrict__ lw_k,
                              const float* __restrict__ lw_v, const float* __restrict__ lb_q,
                              const float* __restrict__ lb_k, const float* __restrict__ lb_v,
                              const float* __restrict__ cw_q, const float* __restrict__ cw_k,
                              const float* __restrict__ cw_v, const float* __restrict__ cb_q,
                              const float* __restrict__ cb_k, const float* __restrict__ cb_v,
                              const float* __restrict__ proj_w,
                              bf16_t* __restrict__ Wt, float* __restrict__ bias,
                              bf16_t* __restrict__ pwt) {
  size_t i = (size_t)blockIdx.x * blockDim.x + threadIdx.x;
  if (i < WT_ELEMS) {
    int kk = (int)(i % DIN);
    int n  = (int)((i / DIN) % DQK);
    int t  = (int)((i / ((size_t)DIN * DQK)) % 3);
    int h  = (int)((i / ((size_t)DIN * DQK * 3)) % NH);
    int s  = (int)(i / ((size_t)DIN * DQK * 3 * NH));
    const float* lw = (s == 0) ? lw_q : ((s == 1) ? lw_k : lw_v);
    const float* cw = (s == 0) ? cw_q : ((s == 1) ? cw_k : cw_v);
    float val;
    if (h < 2) val = (t == 1) ? lw[((size_t)h * DIN + kk) * DQK + n] : 0.f;
    else       val = cw[(((size_t)(h - 2) * DQK + n) * DIN + kk) * 3 + t];
    Wt[i] = (bf16_t)val;
  } else if (i < WT_ELEMS + PWT_ELEMS) {
    size_t j = i - WT_ELEMS;
    int n = (int)(j / DIN), kk = (int)(j % DIN);
    pwt[j] = (bf16_t)proj_w[(size_t)kk * DIN + n];
  } else if (i < WT_ELEMS + PWT_ELEMS + BIAS_ELEMS) {
    size_t j = i - WT_ELEMS - PWT_ELEMS;
    int s = (int)(j / (NH * DQK));
    int h = (int)((j / DQK) % NH);
    int n = (int)(j % DQK);
    const float* lb = (s == 0) ? lb_q : ((s == 1) ? lb_k : lb_v);
    const float* cb = (s == 0) ? cb_q : ((s == 1) ? cb_k : cb_v);
    bias[j] = (h < 2) ? lb[h * DQK + n] : cb[(h - 2) * DQK + n];
  }
}

// --------------------------- projection GEMM -------------------------------
// z = s*4 + h'. Conv heads: sum of 3 shifted GEMMs over the padded input.
// Q/K -> [h][b][l][dqk] bf16 ; V -> [h][b][dqk][l] bf16 (transposed for att*V)
// h' remap (z&3)^2 dispatches the 3x-longer conv blocks first (tail shrink).
__global__ __launch_bounds__(256, 2) void proj_kernel(
    const bf16_t* __restrict__ xpad, const bf16_t* __restrict__ Wt,
    const float* __restrict__ bias,
    bf16_t* __restrict__ Qh, bf16_t* __restrict__ Kh, bf16_t* __restrict__ Vt) {
  GEMM_PROLOGUE();
  const int mt = blockIdx.x;         // 0..127 (M=16384)
  const int z  = blockIdx.z;         // 0..11
  const int s  = z >> 2, h = (z & 3) ^ 2;   // conv heads (h=2,3) dispatch first
  const int b  = mt >> 3;
  const int l0 = (mt & 7) << 7;

  const bf16_t* Xs = xpad + (size_t)s * XPAD_PER;
  const int t0 = (h < 2) ? 1 : 0;
  const int t1 = (h < 2) ? 1 : 2;
  for (int t = t0; t <= t1; ++t) {
    const bf16_t* Ab = Xs + ((size_t)b * (SL + 2) + l0 + t) * DIN;
    const bf16_t* Bb = Wt + (((size_t)(s * NH + h) * 3 + t) * DQK) * DIN;
    gemm_core(Ab, DIN, Bb, DIN, DIN, acc, lgA, lgB);
  }

  EPILOGUE_VARS();
  const float* bs = bias + (s * NH + h) * DQK;
  if (s < 2) {
    bf16_t* outp = ((s == 0) ? Qh : Kh) + ((size_t)h * NB + b) * SL * DQK
                 + (size_t)l0 * DQK;
#pragma unroll
    for (int mi = 0; mi < 4; ++mi)
#pragma unroll
      for (int ni = 0; ni < 4; ++ni)
#pragma unroll
        for (int r = 0; r < 4; ++r) {
          int row = wr * 64 + mi * 16 + quad * 4 + r;
          int col = wc * 64 + ni * 16 + l16;
          outp[(size_t)row * DQK + col] = (bf16_t)(acc[mi][ni][r] + bs[col]);
        }
  } else {
    bf16_t* outv = Vt + ((size_t)h * NB + b) * DQK * SL;
#pragma unroll
    for (int mi = 0; mi < 4; ++mi)
#pragma unroll
      for (int ni = 0; ni < 4; ++ni)
#pragma unroll
        for (int r = 0; r < 4; ++r) {
          int row = wr * 64 + mi * 16 + quad * 4 + r;
          int col = wc * 64 + ni * 16 + l16;
          outv[(size_t)col * SL + l0 + row] = (bf16_t)(acc[mi][ni][r] + bs[col]);
        }
  }
}

// ------------------- fused flash attention (QK^T+softmax+PV) ---------------
// Block = (hb, 64 Q-rows). 4 waves; wave w owns rows [w*16, w*16+16) -> the
// softmax row-reduce is wave-local (16-lane shfl groups), no cross-wave sync.
// stKV (32 KB) stages K then V per 128-col tile; eL (16 KB) carries p-bf16
// from the softmax to the PV A-operand. All LDS accesses 16B-slot XOR-swizzled
// (slot ^= row&15), achieved on the staging side by pre-swizzling the GLOBAL
// source address (global_load_lds dest must stay linear).
// Pass1: running (M, sum-e) per row in regs. Pass2: recompute S, emit
// p = exp(s-M)/S -> f32 att output (mandatory) + bf16 eL -> PV MFMA.
__global__ __launch_bounds__(256, 3) void fattn_kernel(
    const bf16_t* __restrict__ Qh, const bf16_t* __restrict__ Kh,
    const bf16_t* __restrict__ Vt,
    const float* __restrict__ lscale, const float* __restrict__ cscale,
    float* __restrict__ att, bf16_t* __restrict__ cat) {
  __shared__ __align__(16) bf16_t stKV[128 * 128];   // 32 KB K/V tile (timeshared)
  __shared__ __align__(16) bf16_t eL[64 * 128];      // 16 KB p tile (swizzled)

  // XCD-friendly decode: blocks with the same hb land on the same XCD
  // (id%8 -> XCD assumption; wrong mapping only costs locality, not correctness)
  const int flat = blockIdx.x;                 // 0..1023
  const int hb   = (flat & 7) * 8 + ((flat >> 3) & 7);
  const int mt   = flat >> 6;                  // 0..15 (64-row tile)
  const int h = hb >> 4, b = hb & 15;

  const int tid  = threadIdx.x;
  const int wave = tid >> 6;
  const int lane = tid & 63;
  const int quad = lane >> 4;
  const int l16  = lane & 15;
  const int row_l = wave * 16 + l16;           // A-frag row (0..63)

  const bf16_t* Qb = Qh + (size_t)hb * SL * DQK + (size_t)(mt * 64) * DQK;
  const bf16_t* Kb = Kh + (size_t)hb * SL * DQK;
  const bf16_t* Vb = Vt + (size_t)hb * DQK * SL;
  float* attp = att + (size_t)hb * SL * SL;

  // Q A-frags in registers: row = row_l, k = kk*32 + quad*8
  bf16x8 af_q[4];
#pragma unroll
  for (int kk = 0; kk < 4; ++kk)
    af_q[kk] = *(const bf16x8*)(Qb + (size_t)row_l * DQK + kk * 32 + quad * 8);

  // stage a 128x128 bf16 tile (rows stride srs elems) into dst, with the 16B
  // slots of each 256B row permuted by slot^=(row&15): linear LDS dest +
  // inverse-permuted global source (rule: swizzle both sides or neither).
#define STAGE_SWZ(srcbase, srs)                                               \
  {                                                                           \
    _Pragma("unroll") for (int i = 0; i < 8; ++i) {                           \
      const int slot = (wave * 8 + i) * 64 + lane;                            \
      const int n = slot >> 4, kc = slot & 15;                                \
      load_lds_16B((srcbase) + (size_t)n * (srs) + ((kc ^ (n & 15)) << 3),    \
                   stKV + (size_t)(wave * 8 + i) * 512);                      \
    }                                                                         \
  }

  // S-tile MFMA: aS[ni] += Q * K, B-frag from swizzled stKV
#define S_MFMA(aS)                                                            \
  {                                                                           \
    _Pragma("unroll") for (int kk = 0; kk < 4; ++kk)                          \
      _Pragma("unroll") for (int ni = 0; ni < 8; ++ni) {                      \
        const int n = ni * 16 + l16;                                          \
        const bf16x8 bf = *(const bf16x8*)((const char*)stKV + n * 256 +      \
                              ((kk * 64 + quad * 16) ^ ((n & 15) << 4)));     \
        aS[ni] = __builtin_amdgcn_mfma_f32_16x16x32_bf16(af_q[kk], bf,        \
                                                         aS[ni], 0, 0, 0);    \
      }                                                                       \
  }

  // ---------------- pass 1: per-row running (max, sum-exp) ----------------
  float M[4], Ssum[4];
#pragma unroll
  for (int r = 0; r < 4; ++r) { M[r] = -3.0e38f; Ssum[r] = 0.f; }

  for (int nt = 0; nt < 8; ++nt) {
    __syncthreads();                          // prev tile's stKV reads done
    STAGE_SWZ(Kb + (size_t)nt * 128 * DQK, DQK);
    __syncthreads();                          // K tile visible
    f32x4 aS[8];
#pragma unroll
    for (int ni = 0; ni < 8; ++ni) aS[ni] = f32x4{0.f, 0.f, 0.f, 0.f};
    S_MFMA(aS);
#pragma unroll
    for (int r = 0; r < 4; ++r) {
      float v[8];
#pragma unroll
      for (int ni = 0; ni < 8; ++ni) v[ni] = aS[ni][r] * INV_SQRT_DK;
      float m = fmaxf(fmaxf(fmaxf(v[0], v[1]), fmaxf(v[2], v[3])),
                      fmaxf(fmaxf(v[4], v[5]), fmaxf(v[6], v[7])));
      m = fmaxf(m, __shfl_xor(m, 1, 64));
      m = fmaxf(m, __shfl_xor(m, 2, 64));
      m = fmaxf(m, __shfl_xor(m, 4, 64));
      m = fmaxf(m, __shfl_xor(m, 8, 64));
      float s = 0.f;
#pragma unroll
      for (int ni = 0; ni < 8; ++ni) s += __expf(v[ni] - m);
      s += __shfl_xor(s, 1, 64);
      s += __shfl_xor(s, 2, 64);
      s += __shfl_xor(s, 4, 64);
      s += __shfl_xor(s, 8, 64);
      const float Mn = fmaxf(M[r], m);
      Ssum[r] = Ssum[r] * __expf(M[r] - Mn) + s * __expf(m - Mn);
      M[r] = Mn;
    }
  }
  float cinv[4];
#pragma unroll
  for (int r = 0; r < 4; ++r) cinv[r] = 1.0f / Ssum[r];

  // ---------------- pass 2: recompute S, emit p, accumulate PV ------------
  f32x4 accO[8];
#pragma unroll
  for (int ni = 0; ni < 8; ++ni) accO[ni] = f32x4{0.f, 0.f, 0.f, 0.f};

  for (int nt = 0; nt < 8; ++nt) {
    __syncthreads();                          // prev tile's V reads done
    STAGE_SWZ(Kb + (size_t)nt * 128 * DQK, DQK);
    __syncthreads();                          // K tile visible
    f32x4 aS[8];
#pragma unroll
    for (int ni = 0; ni < 8; ++ni) aS[ni] = f32x4{0.f, 0.f, 0.f, 0.f};
    S_MFMA(aS);
    // p = exp(s - M) / S : f32 att output + bf16 into swizzled eL
#pragma unroll
    for (int r = 0; r < 4; ++r) {
      const int rowl  = wave * 16 + quad * 4 + r;      // 0..63
      const int row_g = mt * 64 + rowl;
      float* rp = attp + (size_t)row_g * SL + nt * 128 + l16;
#pragma unroll
      for (int ni = 0; ni < 8; ++ni) {
        const float p = __expf(aS[ni][r] * INV_SQRT_DK - M[r]) * cinv[r];
        rp[ni * 16] = p;
        *(bf16_t*)((char*)eL + rowl * 256 +
                   (((ni * 16 + l16) * 2) ^ ((rowl & 15) << 4))) = (bf16_t)p;
      }
    }
    __syncthreads();                          // all waves done reading K tile
    STAGE_SWZ(Vb + (size_t)nt * 128, SL);
    __syncthreads();                          // V tile visible
    // PV: accO += p * V   (eL reads are same-wave RAW -> in-order DS, no bar)
#pragma unroll
    for (int kk = 0; kk < 4; ++kk) {
      const bf16x8 ap = *(const bf16x8*)((const char*)eL + row_l * 256 +
                            ((kk * 64 + quad * 16) ^ ((row_l & 15) << 4)));
#pragma unroll
      for (int ni = 0; ni < 8; ++ni) {
        const int d = ni * 16 + l16;
        const bf16x8 bv = *(const bf16x8*)((const char*)stKV + d * 256 +
                              ((kk * 64 + quad * 16) ^ ((d & 15) << 4)));
        accO[ni] = __builtin_amdgcn_mfma_f32_16x16x32_bf16(ap, bv, accO[ni],
                                                           0, 0, 0);
      }
    }
  }

  // ---------------- epilogue: cat = scale * O -----------------------------
  const float sc = (h < 2) ? lscale[h] : cscale[h - 2];
  bf16_t* outp = cat + (size_t)b * SL * (NH * DQK) + h * DQK;
#pragma unroll
  for (int r = 0; r < 4; ++r) {
    const int row_g = mt * 64 + wave * 16 + quad * 4 + r;
#pragma unroll
    for (int ni = 0; ni < 8; ++ni) {
      const int col = ni * 16 + l16;
      outp[(size_t)row_g * (NH * DQK) + col] = (bf16_t)(accO[ni][r] * sc);
    }
  }
#undef STAGE_SWZ
#undef S_MFMA
}

// --------------------------- final projection ------------------------------
__global__ __launch_bounds__(256, 2) void final_kernel(
    const bf16_t* __restrict__ cat, const bf16_t* __restrict__ pwt,
    const float* __restrict__ pb, float* __restrict__ outp) {
  GEMM_PROLOGUE();
  const int mt = blockIdx.x;   // 0..127
  const int nt = blockIdx.y;   // 0..3
  const bf16_t* Ab = cat + (size_t)mt * 128 * DIN;
  const bf16_t* Bb = pwt + (size_t)nt * 128 * DIN;
  gemm_core(Ab, DIN, Bb, DIN, DIN, acc, lgA, lgB);

  EPILOGUE_VARS();
#pragma unroll
  for (int mi = 0; mi < 4; ++mi)
#pragma unroll
    for (int ni = 0; ni < 4; ++ni)
#pragma unroll
      for (int r = 0; r < 4; ++r) {
        int row = mt * 128 + wr * 64 + mi * 16 + quad * 4 + r;
        int col = nt * 128 + wc * 64 + ni * 16 + l16;
        outp[(size_t)row * DIN + col] = acc[mi][ni][r] + pb[nt * 128 + col];
      }
}

// ---------------------------------------------------------------------------

extern "C" void kernel_launch(void* const* d_in, const int* in_sizes, int n_in,
                              void* d_out, int out_size, void* d_ws, size_t ws_size,
                              hipStream_t stream) {
  const float* q      = (const float*)d_in[0];
  const float* k      = (const float*)d_in[1];
  const float* v      = (const float*)d_in[2];
  const float* lw_q   = (const float*)d_in[3];
  const float* lb_q   = (const float*)d_in[4];
  const float* lw_k   = (const float*)d_in[5];
  const float* lb_k   = (const float*)d_in[6];
  const float* lw_v   = (const float*)d_in[7];
  const float* lb_v   = (const float*)d_in[8];
  const float* lscale = (const float*)d_in[9];
  const float* cw_q   = (const float*)d_in[10];
  const float* cb_q   = (const float*)d_in[11];
  const float* cw_k   = (const float*)d_in[12];
  const float* cb_k   = (const float*)d_in[13];
  const float* cw_v   = (const float*)d_in[14];
  const float* cb_v   = (const float*)d_in[15];
  const float* cscale = (const float*)d_in[16];
  const float* proj_w = (const float*)d_in[17];
  const float* proj_b = (const float*)d_in[18];

  char* ws = (char*)d_ws;
  size_t off = 0;
  bf16_t* xpad = (bf16_t*)(ws + off); off += XPAD_ELEMS * 2;   // 50.4 MB
  bf16_t* Wt   = (bf16_t*)(ws + off); off += WT_ELEMS * 2;     //  4.7 MB
  float*  bias = (float*) (ws + off); off += BIAS_ELEMS * 4;
  bf16_t* pwt  = (bf16_t*)(ws + off); off += PWT_ELEMS * 2;
  bf16_t* Qh   = (bf16_t*)(ws + off); off += QH_ELEMS * 2;     // 16.8 MB
  bf16_t* Kh   = (bf16_t*)(ws + off); off += QH_ELEMS * 2;     // 16.8 MB
  bf16_t* Vt   = (bf16_t*)(ws + off); off += QH_ELEMS * 2;     // 16.8 MB
  bf16_t* cat  = (bf16_t*)(ws + off); off += CAT_ELEMS * 2;    // 16.8 MB
  // total ~123 MB of d_ws

  float* outp = (float*)d_out;
  float* att  = outp + (size_t)NB * SL * DIN;   // 4x[16,1024,1024] f32 region

  {
    int nblk = (int)((XPAD_ELEMS / 8 + 255) / 256);
    cast_pad_kernel<<<nblk, 256, 0, stream>>>(q, k, v, xpad);
  }
  {
    size_t tot = WT_ELEMS + PWT_ELEMS + BIAS_ELEMS;
    int nblk = (int)((tot + 255) / 256);
    prep_w_kernel<<<nblk, 256, 0, stream>>>(lw_q, lw_k, lw_v, lb_q, lb_k, lb_v,
                                            cw_q, cw_k, cw_v, cb_q, cb_k, cb_v,
                                            proj_w, Wt, bias, pwt);
  }
  proj_kernel<<<dim3(128, 1, 12), 256, 0, stream>>>(xpad, Wt, bias, Qh, Kh, Vt);
  fattn_kernel<<<dim3(1024, 1, 1), 256, 0, stream>>>(Qh, Kh, Vt, lscale, cscale,
                                                     att, cat);
  final_kernel<<<dim3(128, 4, 1), 256, 0, stream>>>(cat, pwt, proj_b, outp);
}

// Round 5
// 571.563 us; speedup vs baseline: 1.2779x; 1.2779x over previous
//
#include <hip/hip_runtime.h>

// ---------------------------------------------------------------------------
// MHAMixer: 2 linear heads + 2 conv1d(k=3) heads -> attention -> concat -> proj
// GEMMs (proj/final): bf16 MFMA 16x16x32, 128x128 tile, BK=32, global_load_lds
// staging (m97 structure), B pre-transposed to [N][K].
// R3/R4: fattn rescheduled to T3-minimal 2-phase. Every global->LDS stage is
// issued BEFORE a compute phase and drained AFTER it (the barrier's implicit
// vmcnt(0) lands on loads that have had a full compute phase in flight).
// Pass1: 1 barrier/tile, K ping-pong across P0/P1. Pass2: phase A {stage V |
// S-MFMA + softmax + eL}, phase B {stage K[nt+1] | att stores + PV-MFMA}.
// Single K home (P0) and V home (P1) suffice: each is dead in the phase its
// successor is staged. att f32 stores moved to phase B (balance phases).
// (R4 = identical resubmit of R3; previous round failed on infrastructure.)
// ---------------------------------------------------------------------------

using bf16_t = __bf16;
using bf16x8 = __attribute__((ext_vector_type(8))) __bf16;
using f32x4  = __attribute__((ext_vector_type(4))) float;

#define NB   16
#define SL   1024
#define DIN  512
#define DQK  128
#define NH   4

#define BK 32

constexpr size_t XPAD_ROWS  = (size_t)NB * (SL + 2);          // 16*1026
constexpr size_t XPAD_PER   = XPAD_ROWS * DIN;                // 8,404,992
constexpr size_t XPAD_ELEMS = 3 * XPAD_PER;
constexpr size_t WT_ELEMS   = (size_t)3 * NH * 3 * DQK * DIN; // 2,359,296
constexpr size_t PWT_ELEMS  = (size_t)DIN * DIN;              // 262,144
constexpr size_t BIAS_ELEMS = (size_t)3 * NH * DQK;           // 1536
constexpr size_t QH_ELEMS   = (size_t)NH * NB * SL * DQK;     // 8,388,608
constexpr size_t CAT_ELEMS  = (size_t)NB * SL * (NH * DQK);   // 8,388,608

#define INV_SQRT_DK 0.08838834764831845f

__device__ __forceinline__ void load_lds_16B(const void* g, void* l) {
  __builtin_amdgcn_global_load_lds((const __attribute__((address_space(1))) void*)g,
                                   (__attribute__((address_space(3))) void*)l, 16, 0, 0);
}

// 128x128 output tile, 4 waves (2x2), each wave 4x4 of 16x16x32 MFMA.
// A: [M][K] row-major (lda elems), Bt: [N][K] row-major (ldb elems). K % 32 == 0.
__device__ __forceinline__ void gemm_core(const bf16_t* __restrict__ Ab, int lda,
                                          const bf16_t* __restrict__ Bb, int ldb,
                                          int K, f32x4 acc[4][4],
                                          bf16_t* lgA, bf16_t* lgB) {
  const int tid  = threadIdx.x;
  const int wave = tid >> 6;
  const int lane = tid & 63;
  const int quad = lane >> 4;
  const int l16  = lane & 15;
  const int wr   = wave >> 1;
  const int wc   = wave & 1;
  const int lrow = lane >> 2;        // 0..15: row within 16-row chunk
  const int lcol = (lane & 3) << 3;  // 0,8,16,24: element offset within row

  for (int k0 = 0; k0 < K; k0 += BK) {
    __syncthreads();   // previous iter's LDS reads done before overwrite
#pragma unroll
    for (int c = 0; c < 2; ++c) {
      const int chunk = wave * 2 + c;           // 8 chunks of 16 rows
      const int r = chunk * 16 + lrow;
      load_lds_16B(Ab + (size_t)r * lda + k0 + lcol, lgA + chunk * 512);
      load_lds_16B(Bb + (size_t)r * ldb + k0 + lcol, lgB + chunk * 512);
    }
    __syncthreads();   // drains vmcnt (compiler) -> LDS tiles visible
    bf16x8 af[4], bfr[4];
#pragma unroll
    for (int i = 0; i < 4; ++i)
      af[i] = *(const bf16x8*)(lgA + (wr * 64 + i * 16 + l16) * BK + quad * 8);
#pragma unroll
    for (int i = 0; i < 4; ++i)
      bfr[i] = *(const bf16x8*)(lgB + (wc * 64 + i * 16 + l16) * BK + quad * 8);
#pragma unroll
    for (int mi = 0; mi < 4; ++mi)
#pragma unroll
      for (int ni = 0; ni < 4; ++ni)
        acc[mi][ni] = __builtin_amdgcn_mfma_f32_16x16x32_bf16(af[mi], bfr[ni],
                                                              acc[mi][ni], 0, 0, 0);
  }
}

#define GEMM_PROLOGUE()                                    \
  __shared__ __align__(16) bf16_t lgA[128 * BK];           \
  __shared__ __align__(16) bf16_t lgB[128 * BK];           \
  f32x4 acc[4][4];                                         \
  {                                                        \
    f32x4 z = {0.f, 0.f, 0.f, 0.f};                        \
    _Pragma("unroll") for (int i = 0; i < 4; ++i)          \
      _Pragma("unroll") for (int j = 0; j < 4; ++j)        \
        acc[i][j] = z;                                     \
  }

#define EPILOGUE_VARS()                                    \
  const int wave = threadIdx.x >> 6;                       \
  const int lane = threadIdx.x & 63;                       \
  const int quad = lane >> 4;                              \
  const int l16  = lane & 15;                              \
  const int wr   = wave >> 1;                              \
  const int wc   = wave & 1;

// --------------------------- prep kernels ----------------------------------

// pad+cast q/k/v -> bf16 [3][NB][1026][DIN], rows 0 and 1025 zeroed per batch
__global__ void cast_pad_kernel(const float* __restrict__ q,
                                const float* __restrict__ k,
                                const float* __restrict__ v,
                                bf16_t* __restrict__ xpad) {
  size_t i = (size_t)blockIdx.x * blockDim.x + threadIdx.x;  // 8-elem group
  if (i >= XPAD_ELEMS / 8) return;
  int    s    = (int)(i / (XPAD_PER / 8));
  size_t r    = i % (XPAD_PER / 8);
  size_t rowg = r >> 6;                 // b*1026 + padded row
  int    c0   = (int)(r & 63) * 8;
  size_t b    = rowg / (SL + 2);
  int    row  = (int)(rowg % (SL + 2));
  const float* src = (s == 0) ? q : ((s == 1) ? k : v);
  bf16x8 o;
  if (row == 0 || row == SL + 1) {
#pragma unroll
    for (int j = 0; j < 8; ++j) o[j] = (bf16_t)0.f;
  } else {
    const float* p = src + ((b * SL) + row - 1) * DIN + c0;
    const float4 f0 = ((const float4*)p)[0];
    const float4 f1 = ((const float4*)p)[1];
    o[0] = (bf16_t)f0.x; o[1] = (bf16_t)f0.y; o[2] = (bf16_t)f0.z; o[3] = (bf16_t)f0.w;
    o[4] = (bf16_t)f1.x; o[5] = (bf16_t)f1.y; o[6] = (bf16_t)f1.z; o[7] = (bf16_t)f1.w;
  }
  *(bf16x8*)(xpad + i * 8) = o;
}

// Wt  [3][4][3][DQK][DIN] bf16 (B^T per src/head/tap; learnable: tap1 only)
// pwt [DIN][DIN] bf16 = proj_w^T ; bias [3][4][DQK] f32
__global__ void prep_w_kernel(const float* __restrict__ lw_q, const float* __restrict__ lw_k,
                              const float* __restrict__ lw_v, const float* __restrict__ lb_q,
                              const float* __restrict__ lb_k, const float* __restrict__ lb_v,
                              const float* __restrict__ cw_q, const float* __restrict__ cw_k,
                              const float* __restrict__ cw_v, const float* __restrict__ cb_q,
                              const float* __restrict__ cb_k, const float* __restrict__ cb_v,
                              const float* __restrict__ proj_w,
                              bf16_t* __restrict__ Wt, float* __restrict__ bias,
                              bf16_t* __restrict__ pwt) {
  size_t i = (size_t)blockIdx.x * blockDim.x + threadIdx.x;
  if (i < WT_ELEMS) {
    int kk = (int)(i % DIN);
    int n  = (int)((i / DIN) % DQK);
    int t  = (int)((i / ((size_t)DIN * DQK)) % 3);
    int h  = (int)((i / ((size_t)DIN * DQK * 3)) % NH);
    int s  = (int)(i / ((size_t)DIN * DQK * 3 * NH));
    const float* lw = (s == 0) ? lw_q : ((s == 1) ? lw_k : lw_v);
    const float* cw = (s == 0) ? cw_q : ((s == 1) ? cw_k : cw_v);
    float val;
    if (h < 2) val = (t == 1) ? lw[((size_t)h * DIN + kk) * DQK + n] : 0.f;
    else       val = cw[(((size_t)(h - 2) * DQK + n) * DIN + kk) * 3 + t];
    Wt[i] = (bf16_t)val;
  } else if (i < WT_ELEMS + PWT_ELEMS) {
    size_t j = i - WT_ELEMS;
    int n = (int)(j / DIN), kk = (int)(j % DIN);
    pwt[j] = (bf16_t)proj_w[(size_t)kk * DIN + n];
  } else if (i < WT_ELEMS + PWT_ELEMS + BIAS_ELEMS) {
    size_t j = i - WT_ELEMS - PWT_ELEMS;
    int s = (int)(j / (NH * DQK));
    int h = (int)((j / DQK) % NH);
    int n = (int)(j % DQK);
    const float* lb = (s == 0) ? lb_q : ((s == 1) ? lb_k : lb_v);
    const float* cb = (s == 0) ? cb_q : ((s == 1) ? cb_k : cb_v);
    bias[j] = (h < 2) ? lb[h * DQK + n] : cb[(h - 2) * DQK + n];
  }
}

// --------------------------- projection GEMM -------------------------------
// z = s*4 + h'. Conv heads: sum of 3 shifted GEMMs over the padded input.
// Q/K -> [h][b][l][dqk] bf16 ; V -> [h][b][dqk][l] bf16 (transposed for att*V)
// h' remap (z&3)^2 dispatches the 3x-longer conv blocks first (tail shrink).
__global__ __launch_bounds__(256, 2) void proj_kernel(
    const bf16_t* __restrict__ xpad, const bf16_t* __restrict__ Wt,
    const float* __restrict__ bias,
    bf16_t* __restrict__ Qh, bf16_t* __restrict__ Kh, bf16_t* __restrict__ Vt) {
  GEMM_PROLOGUE();
  const int mt = blockIdx.x;         // 0..127 (M=16384)
  const int z  = blockIdx.z;         // 0..11
  const int s  = z >> 2, h = (z & 3) ^ 2;   // conv heads (h=2,3) dispatch first
  const int b  = mt >> 3;
  const int l0 = (mt & 7) << 7;

  const bf16_t* Xs = xpad + (size_t)s * XPAD_PER;
  const int t0 = (h < 2) ? 1 : 0;
  const int t1 = (h < 2) ? 1 : 2;
  for (int t = t0; t <= t1; ++t) {
    const bf16_t* Ab = Xs + ((size_t)b * (SL + 2) + l0 + t) * DIN;
    const bf16_t* Bb = Wt + (((size_t)(s * NH + h) * 3 + t) * DQK) * DIN;
    gemm_core(Ab, DIN, Bb, DIN, DIN, acc, lgA, lgB);
  }

  EPILOGUE_VARS();
  const float* bs = bias + (s * NH + h) * DQK;
  if (s < 2) {
    bf16_t* outp = ((s == 0) ? Qh : Kh) + ((size_t)h * NB + b) * SL * DQK
                 + (size_t)l0 * DQK;
#pragma unroll
    for (int mi = 0; mi < 4; ++mi)
#pragma unroll
      for (int ni = 0; ni < 4; ++ni)
#pragma unroll
        for (int r = 0; r < 4; ++r) {
          int row = wr * 64 + mi * 16 + quad * 4 + r;
          int col = wc * 64 + ni * 16 + l16;
          outp[(size_t)row * DQK + col] = (bf16_t)(acc[mi][ni][r] + bs[col]);
        }
  } else {
    bf16_t* outv = Vt + ((size_t)h * NB + b) * DQK * SL;
#pragma unroll
    for (int mi = 0; mi < 4; ++mi)
#pragma unroll
      for (int ni = 0; ni < 4; ++ni)
#pragma unroll
        for (int r = 0; r < 4; ++r) {
          int row = wr * 64 + mi * 16 + quad * 4 + r;
          int col = wc * 64 + ni * 16 + l16;
          outv[(size_t)col * SL + l0 + row] = (bf16_t)(acc[mi][ni][r] + bs[col]);
        }
  }
}

// ------------------- fused flash attention (QK^T+softmax+PV) ---------------
// Block = (hb, 64 Q-rows). 4 waves; wave w owns rows [w*16, w*16+16) -> the
// softmax row-reduce is wave-local (16-lane shfl groups). LDS: P0 (32 KB,
// pass2 K home), P1 (32 KB, pass2 V home), eL (16 KB p-bf16). 80 KB ->
// 2 blocks/CU. All LDS accesses 16B-slot XOR-swizzled (slot ^= row&15) via
// pre-swizzled GLOBAL source (global_load_lds dest stays linear).
// T3-minimal schedule: each stage issued before a compute phase, drained by
// the barrier after it -- the vmcnt(0) drain always overlaps ~a full phase.
__global__ __launch_bounds__(256, 2) void fattn_kernel(
    const bf16_t* __restrict__ Qh, const bf16_t* __restrict__ Kh,
    const bf16_t* __restrict__ Vt,
    const float* __restrict__ lscale, const float* __restrict__ cscale,
    float* __restrict__ att, bf16_t* __restrict__ cat) {
  __shared__ __align__(16) bf16_t P0[128 * 128];   // 32 KB (pass2: K home)
  __shared__ __align__(16) bf16_t P1[128 * 128];   // 32 KB (pass2: V home)
  __shared__ __align__(16) bf16_t eL[64 * 128];    // 16 KB p tile (swizzled)

  // XCD-friendly decode: blocks with the same hb land on the same XCD
  const int flat = blockIdx.x;                 // 0..1023
  const int hb   = (flat & 7) * 8 + ((flat >> 3) & 7);
  const int mt   = flat >> 6;                  // 0..15 (64-row tile)
  const int h = hb >> 4, b = hb & 15;

  const int tid  = threadIdx.x;
  const int wave = tid >> 6;
  const int lane = tid & 63;
  const int quad = lane >> 4;
  const int l16  = lane & 15;
  const int row_l = wave * 16 + l16;           // A-frag row (0..63)

  const bf16_t* Qb = Qh + (size_t)hb * SL * DQK + (size_t)(mt * 64) * DQK;
  const bf16_t* Kb = Kh + (size_t)hb * SL * DQK;
  const bf16_t* Vb = Vt + (size_t)hb * DQK * SL;
  float* attp = att + (size_t)hb * SL * SL;

  // Q A-frags in registers: row = row_l, k = kk*32 + quad*8
  bf16x8 af_q[4];
#pragma unroll
  for (int kk = 0; kk < 4; ++kk)
    af_q[kk] = *(const bf16x8*)(Qb + (size_t)row_l * DQK + kk * 32 + quad * 8);

  // stage a 128x128 bf16 tile (rows stride srs elems) into dst, with the 16B
  // slots of each 256B row permuted by slot^=(row&15): linear LDS dest +
  // inverse-permuted global source (rule: swizzle both sides or neither).
#define STAGE_SWZ(dst, srcbase, srs)                                          \
  {                                                                           \
    _Pragma("unroll") for (int i = 0; i < 8; ++i) {                           \
      const int slot = (wave * 8 + i) * 64 + lane;                            \
      const int n = slot >> 4, kc = slot & 15;                                \
      load_lds_16B((srcbase) + (size_t)n * (srs) + ((kc ^ (n & 15)) << 3),    \
                   (dst) + (size_t)(wave * 8 + i) * 512);                     \
    }                                                                         \
  }

  // S-tile MFMA: aS[ni] += Q * K, B-frag from swizzled buffer
#define S_MFMA(aS, buf)                                                       \
  {                                                                           \
    _Pragma("unroll") for (int kk = 0; kk < 4; ++kk)                          \
      _Pragma("unroll") for (int ni = 0; ni < 8; ++ni) {                      \
        const int n = ni * 16 + l16;                                          \
        const bf16x8 bf = *(const bf16x8*)((const char*)(buf) + n * 256 +     \
                              ((kk * 64 + quad * 16) ^ ((n & 15) << 4)));     \
        aS[ni] = __builtin_amdgcn_mfma_f32_16x16x32_bf16(af_q[kk], bf,        \
                                                         aS[ni], 0, 0, 0);    \
      }                                                                       \
  }

  // ---------------- pass 1: per-row running (max, sum-exp) ----------------
  // K ping-pong P0/P1; stage K[nt+1] issued before compute on K[nt], drained
  // by the barrier after it. nt=7 stages K[0] -> P0 = pass2's K home.
  float M[4], Ssum[4];
#pragma unroll
  for (int r = 0; r < 4; ++r) { M[r] = -3.0e38f; Ssum[r] = 0.f; }

  STAGE_SWZ(P0, Kb, DQK);                      // K[0] -> P0
  __syncthreads();                             // prologue drain (unavoidable)

  for (int nt = 0; nt < 8; ++nt) {
    bf16_t* cur  = (nt & 1) ? P1 : P0;
    bf16_t* nxtb = (nt & 1) ? P0 : P1;
    STAGE_SWZ(nxtb, Kb + (size_t)((nt + 1) & 7) * 128 * DQK, DQK);
    f32x4 aS[8];
#pragma unroll
    for (int ni = 0; ni < 8; ++ni) aS[ni] = f32x4{0.f, 0.f, 0.f, 0.f};
    S_MFMA(aS, cur);
#pragma unroll
    for (int r = 0; r < 4; ++r) {
      float v[8];
#pragma unroll
      for (int ni = 0; ni < 8; ++ni) v[ni] = aS[ni][r] * INV_SQRT_DK;
      float m = fmaxf(fmaxf(fmaxf(v[0], v[1]), fmaxf(v[2], v[3])),
                      fmaxf(fmaxf(v[4], v[5]), fmaxf(v[6], v[7])));
      m = fmaxf(m, __shfl_xor(m, 1, 64));
      m = fmaxf(m, __shfl_xor(m, 2, 64));
      m = fmaxf(m, __shfl_xor(m, 4, 64));
      m = fmaxf(m, __shfl_xor(m, 8, 64));
      float s = 0.f;
#pragma unroll
      for (int ni = 0; ni < 8; ++ni) s += __expf(v[ni] - m);
      s += __shfl_xor(s, 1, 64);
      s += __shfl_xor(s, 2, 64);
      s += __shfl_xor(s, 4, 64);
      s += __shfl_xor(s, 8, 64);
      const float Mn = fmaxf(M[r], m);
      Ssum[r] = Ssum[r] * __expf(M[r] - Mn) + s * __expf(m - Mn);
      M[r] = Mn;
    }
    __syncthreads();   // drains K[nt+1] stage; cur reads done before overwrite
  }
  float cinv[4];
#pragma unroll
  for (int r = 0; r < 4; ++r) cinv[r] = 1.0f / Ssum[r];

  // ---------------- pass 2: recompute S, emit p, accumulate PV ------------
  // K[0] already resident in P0 (staged during pass1's last phase).
  f32x4 accO[8];
#pragma unroll
  for (int ni = 0; ni < 8; ++ni) accO[ni] = f32x4{0.f, 0.f, 0.f, 0.f};

  for (int nt = 0; nt < 8; ++nt) {
    // ---- phase A: stage V[nt] -> P1 | S-MFMA(P0) + softmax -> aS=p + eL ----
    STAGE_SWZ(P1, Vb + (size_t)nt * 128, SL);
    f32x4 aS[8];
#pragma unroll
    for (int ni = 0; ni < 8; ++ni) aS[ni] = f32x4{0.f, 0.f, 0.f, 0.f};
    S_MFMA(aS, P0);
#pragma unroll
    for (int r = 0; r < 4; ++r) {
      const int rowl = wave * 16 + quad * 4 + r;       // 0..63
#pragma unroll
      for (int ni = 0; ni < 8; ++ni) {
        const float p = __expf(aS[ni][r] * INV_SQRT_DK - M[r]) * cinv[r];
        aS[ni][r] = p;                                 // carry p into phase B
        *(bf16_t*)((char*)eL + rowl * 256 +
                   (((ni * 16 + l16) * 2) ^ ((rowl & 15) << 4))) = (bf16_t)p;
      }
    }
    __syncthreads();   // drains V stage; all waves' P0 reads done; eL visible

    // ---- phase B: stage K[nt+1] -> P0 | att f32 stores + PV-MFMA(P1,eL) ---
    if (nt < 7) STAGE_SWZ(P0, Kb + (size_t)(nt + 1) * 128 * DQK, DQK);
#pragma unroll
    for (int r = 0; r < 4; ++r) {
      const int row_g = mt * 64 + wave * 16 + quad * 4 + r;
      float* rp = attp + (size_t)row_g * SL + nt * 128 + l16;
#pragma unroll
      for (int ni = 0; ni < 8; ++ni) rp[ni * 16] = aS[ni][r];
    }
#pragma unroll
    for (int kk = 0; kk < 4; ++kk) {
      const bf16x8 ap = *(const bf16x8*)((const char*)eL + row_l * 256 +
                            ((kk * 64 + quad * 16) ^ ((row_l & 15) << 4)));
#pragma unroll
      for (int ni = 0; ni < 8; ++ni) {
        const int d = ni * 16 + l16;
        const bf16x8 bv = *(const bf16x8*)((const char*)P1 + d * 256 +
                              ((kk * 64 + quad * 16) ^ ((d & 15) << 4)));
        accO[ni] = __builtin_amdgcn_mfma_f32_16x16x32_bf16(ap, bv, accO[ni],
                                                           0, 0, 0);
      }
    }
    __syncthreads();   // drains K[nt+1]; P1/eL reads done before next phase A
  }

  // ---------------- epilogue: cat = scale * O -----------------------------
  const float sc = (h < 2) ? lscale[h] : cscale[h - 2];
  bf16_t* outp = cat + (size_t)b * SL * (NH * DQK) + h * DQK;
#pragma unroll
  for (int r = 0; r < 4; ++r) {
    const int row_g = mt * 64 + wave * 16 + quad * 4 + r;
#pragma unroll
    for (int ni = 0; ni < 8; ++ni) {
      const int col = ni * 16 + l16;
      outp[(size_t)row_g * (NH * DQK) + col] = (bf16_t)(accO[ni][r] * sc);
    }
  }
#undef STAGE_SWZ
#undef S_MFMA
}

// --------------------------- final projection ------------------------------
__global__ __launch_bounds__(256, 2) void final_kernel(
    const bf16_t* __restrict__ cat, const bf16_t* __restrict__ pwt,
    const float* __restrict__ pb, float* __restrict__ outp) {
  GEMM_PROLOGUE();
  const int mt = blockIdx.x;   // 0..127
  const int nt = blockIdx.y;   // 0..3
  const bf16_t* Ab = cat + (size_t)mt * 128 * DIN;
  const bf16_t* Bb = pwt + (size_t)nt * 128 * DIN;
  gemm_core(Ab, DIN, Bb, DIN, DIN, acc, lgA, lgB);

  EPILOGUE_VARS();
#pragma unroll
  for (int mi = 0; mi < 4; ++mi)
#pragma unroll
    for (int ni = 0; ni < 4; ++ni)
#pragma unroll
      for (int r = 0; r < 4; ++r) {
        int row = mt * 128 + wr * 64 + mi * 16 + quad * 4 + r;
        int col = nt * 128 + wc * 64 + ni * 16 + l16;
        outp[(size_t)row * DIN + col] = acc[mi][ni][r] + pb[nt * 128 + col];
      }
}

// ---------------------------------------------------------------------------

extern "C" void kernel_launch(void* const* d_in, const int* in_sizes, int n_in,
                              void* d_out, int out_size, void* d_ws, size_t ws_size,
                              hipStream_t stream) {
  const float* q      = (const float*)d_in[0];
  const float* k      = (const float*)d_in[1];
  const float* v      = (const float*)d_in[2];
  const float* lw_q   = (const float*)d_in[3];
  const float* lb_q   = (const float*)d_in[4];
  const float* lw_k   = (const float*)d_in[5];
  const float* lb_k   = (const float*)d_in[6];
  const float* lw_v   = (const float*)d_in[7];
  const float* lb_v   = (const float*)d_in[8];
  const float* lscale = (const float*)d_in[9];
  const float* cw_q   = (const float*)d_in[10];
  const float* cb_q   = (const float*)d_in[11];
  const float* cw_k   = (const float*)d_in[12];
  const float* cb_k   = (const float*)d_in[13];
  const float* cw_v   = (const float*)d_in[14];
  const float* cb_v   = (const float*)d_in[15];
  const float* cscale = (const float*)d_in[16];
  const float* proj_w = (const float*)d_in[17];
  const float* proj_b = (const float*)d_in[18];

  char* ws = (char*)d_ws;
  size_t off = 0;
  bf16_t* xpad = (bf16_t*)(ws + off); off += XPAD_ELEMS * 2;   // 50.4 MB
  bf16_t* Wt   = (bf16_t*)(ws + off); off += WT_ELEMS * 2;     //  4.7 MB
  float*  bias = (float*) (ws + off); off += BIAS_ELEMS * 4;
  bf16_t* pwt  = (bf16_t*)(ws + off); off += PWT_ELEMS * 2;
  bf16_t* Qh   = (bf16_t*)(ws + off); off += QH_ELEMS * 2;     // 16.8 MB
  bf16_t* Kh   = (bf16_t*)(ws + off); off += QH_ELEMS * 2;     // 16.8 MB
  bf16_t* Vt   = (bf16_t*)(ws + off); off += QH_ELEMS * 2;     // 16.8 MB
  bf16_t* cat  = (bf16_t*)(ws + off); off += CAT_ELEMS * 2;    // 16.8 MB
  // total ~123 MB of d_ws

  float* outp = (float*)d_out;
  float* att  = outp + (size_t)NB * SL * DIN;   // 4x[16,1024,1024] f32 region

  {
    int nblk = (int)((XPAD_ELEMS / 8 + 255) / 256);
    cast_pad_kernel<<<nblk, 256, 0, stream>>>(q, k, v, xpad);
  }
  {
    size_t tot = WT_ELEMS + PWT_ELEMS + BIAS_ELEMS;
    int nblk = (int)((tot + 255) / 256);
    prep_w_kernel<<<nblk, 256, 0, stream>>>(lw_q, lw_k, lw_v, lb_q, lb_k, lb_v,
                                            cw_q, cw_k, cw_v, cb_q, cb_k, cb_v,
                                            proj_w, Wt, bias, pwt);
  }
  proj_kernel<<<dim3(128, 1, 12), 256, 0, stream>>>(xpad, Wt, bias, Qh, Kh, Vt);
  fattn_kernel<<<dim3(1024, 1, 1), 256, 0, stream>>>(Qh, Kh, Vt, lscale, cscale,
                                                     att, cat);
  final_kernel<<<dim3(128, 4, 1), 256, 0, stream>>>(cat, pwt, proj_b, outp);
}